// Round 1
// baseline (536.051 us; speedup 1.0000x reference)
//
#include <hip/hip_runtime.h>
#include <hip/hip_bf16.h>

// Problem constants (match reference)
#define BB 512
#define CC 112
#define DD 128
#define HH 8
#define HD 16
#define KK 8

// ---------------------------------------------------------------------------
// K1: src = x + BN(GELU(depthwise_conv1d(x, k=8, pad (3,4)) + b))
// One 128-thread block per (b,c) row; conv is along D within the row.
// ---------------------------------------------------------------------------
__global__ __launch_bounds__(128) void k_conv(
    const float* __restrict__ x, const float* __restrict__ cw,
    const float* __restrict__ cb, const float* __restrict__ bg,
    const float* __restrict__ bb_, const float* __restrict__ bm,
    const float* __restrict__ bv, float* __restrict__ src) {
  const int row = blockIdx.x;          // b*CC + c
  const int c = row % CC;
  const int d = threadIdx.x;           // 0..127
  __shared__ float sx[DD];
  const size_t base = (size_t)row * DD;
  const float xv = x[base + d];
  sx[d] = xv;
  __syncthreads();
  float acc = 0.f;
#pragma unroll
  for (int k = 0; k < KK; ++k) {
    const int j = d - 3 + k;           // torch 'same' even-k: left pad 3
    const float xn = (j >= 0 && j < DD) ? sx[j] : 0.f;
    acc = fmaf(xn, cw[c * KK + k], acc);
  }
  acc += cb[c];
  // exact GELU
  const float g = 0.5f * acc * (1.f + erff(acc * 0.70710678118654752440f));
  const float h = (g - bm[c]) * (bg[c] * rsqrtf(bv[c] + 1e-5f)) + bb_[c];
  src[base + d] = xv + h;
}

// ---------------------------------------------------------------------------
// K2: q/k/v = src @ w.T + b.  Block: 256 threads, 32-row M-tile, all 128 cols.
// Weights staged in LDS in two K-halves (keeps static LDS < 64 KB).
// Register tile 4x4 per thread -> 0.5 LDS reads per FMA.
// ---------------------------------------------------------------------------
__global__ __launch_bounds__(256) void k_qkv(
    const float* __restrict__ src,
    const float* __restrict__ wq, const float* __restrict__ bq,
    const float* __restrict__ wk, const float* __restrict__ bk,
    const float* __restrict__ wv, const float* __restrict__ bv,
    float* __restrict__ q, float* __restrict__ k, float* __restrict__ v) {
  __shared__ __attribute__((aligned(16))) float s_a[32][132];  // src tile
  __shared__ __attribute__((aligned(16))) float s_w[128][68];  // weight K-half
  const int t = threadIdx.x;
  const int row0 = blockIdx.x * 32;
  // load 32 src rows (32x32 float4)
  for (int i = t; i < 32 * 32; i += 256) {
    const int r = i >> 5, c4 = i & 31;
    const float4 val = ((const float4*)(src + (size_t)(row0 + r) * DD))[c4];
    *(float4*)&s_a[r][c4 * 4] = val;
  }
  const float* const wp[3] = {wq, wk, wv};
  const float* const bp[3] = {bq, bk, bv};
  float* const op[3] = {q, k, v};
  const int tr = t >> 5;   // 0..7  -> rows tr + 8*i
  const int tc = t & 31;   // 0..31 -> cols tc + 32*i
  for (int m = 0; m < 3; ++m) {
    float acc[4][4];
#pragma unroll
    for (int a = 0; a < 4; ++a)
#pragma unroll
      for (int b2 = 0; b2 < 4; ++b2) acc[a][b2] = 0.f;
    const float* __restrict__ w = wp[m];
    for (int p = 0; p < 2; ++p) {
      __syncthreads();  // protect s_w reuse (and s_a load on first pass)
      for (int i = t; i < 128 * 16; i += 256) {
        const int r = i >> 4, c4 = i & 15;
        const float4 val =
            ((const float4*)(w + (size_t)r * DD + p * 64))[c4];
        *(float4*)&s_w[r][c4 * 4] = val;
      }
      __syncthreads();
      for (int j = 0; j < 64; j += 4) {
        float4 av[4], wv4[4];
#pragma unroll
        for (int i = 0; i < 4; ++i) {
          av[i]  = *(const float4*)&s_a[tr + 8 * i][p * 64 + j];
          wv4[i] = *(const float4*)&s_w[tc + 32 * i][j];
        }
#pragma unroll
        for (int a = 0; a < 4; ++a) {
          const float* ap = (const float*)&av[a];
#pragma unroll
          for (int b2 = 0; b2 < 4; ++b2) {
            const float* wpp = (const float*)&wv4[b2];
#pragma unroll
            for (int jj = 0; jj < 4; ++jj)
              acc[a][b2] = fmaf(ap[jj], wpp[jj], acc[a][b2]);
          }
        }
      }
    }
    float* __restrict__ o = op[m];
    const float* __restrict__ bias = bp[m];
#pragma unroll
    for (int a = 0; a < 4; ++a) {
      const size_t rbase = (size_t)(row0 + tr + 8 * a) * DD;
#pragma unroll
      for (int b2 = 0; b2 < 4; ++b2) {
        const int col = tc + 32 * b2;
        o[rbase + col] = acc[a][b2] + bias[col];
      }
    }
  }
}

// ---------------------------------------------------------------------------
// K3: attention for one (b,h).  q,k,v staged transposed [e][c] in LDS.
// Scores processed in two 56-row halves (keeps static LDS < 64 KB).
// Output written IN PLACE over the q buffer slice (only this block touches it).
// ---------------------------------------------------------------------------
__global__ __launch_bounds__(256) void k_attn(
    float* __restrict__ gq, const float* __restrict__ gk,
    const float* __restrict__ gv) {
  const int b = blockIdx.x >> 3;
  const int h = blockIdx.x & 7;
  const int t = threadIdx.x;
  __shared__ __attribute__((aligned(16))) float sqT[HD][116];
  __shared__ __attribute__((aligned(16))) float skT[HD][116];
  __shared__ __attribute__((aligned(16))) float svT[HD][116];
  __shared__ __attribute__((aligned(16))) float ss[56][116];
  __shared__ float rinv[56];
  const size_t base = (size_t)b * CC * DD + (size_t)h * HD;
  for (int idx = t; idx < CC * HD; idx += 256) {
    const int c = idx >> 4, e = idx & 15;
    const size_t g = base + (size_t)c * DD + e;
    sqT[e][c] = gq[g];
    skT[e][c] = gk[g];
    svT[e][c] = gv[g];
  }
  for (int half = 0; half < 2; ++half) {
    const int i0b = half * 56;
    __syncthreads();  // staging done / previous half's out done
    // scores: 14x28 tiles of 4x4 over (i,j)
    for (int tt = t; tt < 14 * 28; tt += 256) {
      const int ti = tt / 28;
      const int tj = tt - ti * 28;
      const int ir = ti * 4;            // row within ss
      const int i0 = i0b + ir;          // absolute query index
      const int j0 = tj * 4;
      float acc[4][4];
#pragma unroll
      for (int a = 0; a < 4; ++a)
#pragma unroll
        for (int b2 = 0; b2 < 4; ++b2) acc[a][b2] = 0.f;
#pragma unroll
      for (int e = 0; e < HD; ++e) {
        const float4 qv = *(const float4*)&sqT[e][i0];
        const float4 kv = *(const float4*)&skT[e][j0];
        const float* qp = (const float*)&qv;
        const float* kp = (const float*)&kv;
#pragma unroll
        for (int a = 0; a < 4; ++a)
#pragma unroll
          for (int b2 = 0; b2 < 4; ++b2)
            acc[a][b2] = fmaf(qp[a], kp[b2], acc[a][b2]);
      }
#pragma unroll
      for (int a = 0; a < 4; ++a) {
        float4 st;
        st.x = acc[a][0] * 0.25f;  // SCALE = HD^-0.5 = 0.25
        st.y = acc[a][1] * 0.25f;
        st.z = acc[a][2] * 0.25f;
        st.w = acc[a][3] * 0.25f;
        *(float4*)&ss[ir + a][j0] = st;
      }
    }
    __syncthreads();
    // softmax per row (unnormalized; 1/sum folded into PV output)
    if (t < 56) {
      float mx = -1e30f;
      for (int j = 0; j < CC; ++j) mx = fmaxf(mx, ss[t][j]);
      float sum = 0.f;
      for (int j = 0; j < CC; ++j) {
        const float e_ = __expf(ss[t][j] - mx);
        ss[t][j] = e_;
        sum += e_;
      }
      rinv[t] = 1.f / sum;
    }
    __syncthreads();
    // out[i][e] = (1/sum_i) * sum_j p[i][j] * v[j][e]
    for (int o = t; o < 56 * HD; o += 256) {
      const int i = o >> 4, e = o & 15;
      float acc = 0.f;
      for (int j = 0; j < CC; j += 4) {
        const float4 pv = *(const float4*)&ss[i][j];
        const float4 vv = *(const float4*)&svT[e][j];
        acc = fmaf(pv.x, vv.x, acc);
        acc = fmaf(pv.y, vv.y, acc);
        acc = fmaf(pv.z, vv.z, acc);
        acc = fmaf(pv.w, vv.w, acc);
      }
      gq[base + (size_t)(i0b + i) * DD + e] = acc * rinv[i];
    }
  }
}

// ---------------------------------------------------------------------------
// K4: out = LayerNorm(src + attn @ wo.T + bo) * ln_g + ln_b
// Same tiling as K2; result staged in LDS for per-row mean/var.
// ---------------------------------------------------------------------------
__global__ __launch_bounds__(256) void k_out(
    const float* __restrict__ attn, const float* __restrict__ src,
    const float* __restrict__ wo, const float* __restrict__ bo,
    const float* __restrict__ lg, const float* __restrict__ lb,
    float* __restrict__ out) {
  __shared__ __attribute__((aligned(16))) float s_a[32][132];
  __shared__ __attribute__((aligned(16))) float s_w[128][68];
  __shared__ float s_mu[32], s_rs[32];
  const int t = threadIdx.x;
  const int row0 = blockIdx.x * 32;
  for (int i = t; i < 32 * 32; i += 256) {
    const int r = i >> 5, c4 = i & 31;
    const float4 val = ((const float4*)(attn + (size_t)(row0 + r) * DD))[c4];
    *(float4*)&s_a[r][c4 * 4] = val;
  }
  const int tr = t >> 5;
  const int tc = t & 31;
  float acc[4][4];
#pragma unroll
  for (int a = 0; a < 4; ++a)
#pragma unroll
    for (int b2 = 0; b2 < 4; ++b2) acc[a][b2] = 0.f;
  for (int p = 0; p < 2; ++p) {
    __syncthreads();
    for (int i = t; i < 128 * 16; i += 256) {
      const int r = i >> 4, c4 = i & 15;
      const float4 val = ((const float4*)(wo + (size_t)r * DD + p * 64))[c4];
      *(float4*)&s_w[r][c4 * 4] = val;
    }
    __syncthreads();
    for (int j = 0; j < 64; j += 4) {
      float4 av[4], wv4[4];
#pragma unroll
      for (int i = 0; i < 4; ++i) {
        av[i]  = *(const float4*)&s_a[tr + 8 * i][p * 64 + j];
        wv4[i] = *(const float4*)&s_w[tc + 32 * i][j];
      }
#pragma unroll
      for (int a = 0; a < 4; ++a) {
        const float* ap = (const float*)&av[a];
#pragma unroll
        for (int b2 = 0; b2 < 4; ++b2) {
          const float* wpp = (const float*)&wv4[b2];
#pragma unroll
          for (int jj = 0; jj < 4; ++jj)
            acc[a][b2] = fmaf(ap[jj], wpp[jj], acc[a][b2]);
        }
      }
    }
  }
  __syncthreads();  // all s_a reads done; safe to overwrite with result
#pragma unroll
  for (int a = 0; a < 4; ++a) {
    const int r = tr + 8 * a;
    const size_t rbase = (size_t)(row0 + r) * DD;
#pragma unroll
    for (int b2 = 0; b2 < 4; ++b2) {
      const int col = tc + 32 * b2;
      s_a[r][col] = src[rbase + col] + acc[a][b2] + bo[col];
    }
  }
  __syncthreads();
  if (t < 32) {
    float sum = 0.f, sq = 0.f;
    for (int j = 0; j < DD; ++j) {
      const float vv = s_a[t][j];
      sum += vv;
      sq = fmaf(vv, vv, sq);
    }
    const float mu = sum * (1.f / DD);
    const float var = sq * (1.f / DD) - mu * mu;
    s_mu[t] = mu;
    s_rs[t] = rsqrtf(var + 1e-5f);
  }
  __syncthreads();
  for (int i = t; i < 32 * DD; i += 256) {
    const int r = i >> 7, c = i & 127;
    out[(size_t)(row0 + r) * DD + c] =
        (s_a[r][c] - s_mu[r]) * s_rs[r] * lg[c] + lb[c];
  }
}

extern "C" void kernel_launch(void* const* d_in, const int* in_sizes, int n_in,
                              void* d_out, int out_size, void* d_ws,
                              size_t ws_size, hipStream_t stream) {
  (void)in_sizes; (void)n_in; (void)out_size; (void)ws_size;
  const float* x   = (const float*)d_in[0];
  const float* cw  = (const float*)d_in[1];
  const float* cb  = (const float*)d_in[2];
  const float* bg  = (const float*)d_in[3];
  const float* bb  = (const float*)d_in[4];
  const float* bm  = (const float*)d_in[5];
  const float* bv  = (const float*)d_in[6];
  const float* wq  = (const float*)d_in[7];
  const float* bq  = (const float*)d_in[8];
  const float* wk  = (const float*)d_in[9];
  const float* bk  = (const float*)d_in[10];
  const float* wv  = (const float*)d_in[11];
  const float* bvv = (const float*)d_in[12];
  const float* wo  = (const float*)d_in[13];
  const float* bo  = (const float*)d_in[14];
  const float* lg  = (const float*)d_in[15];
  const float* lb  = (const float*)d_in[16];
  float* out = (float*)d_out;
  float* ws  = (float*)d_ws;

  const size_t NE = (size_t)BB * CC * DD;  // 7,340,032 elems
  float* s_src = ws;            // [B*C, D] fp32
  float* s_q   = ws + NE;       // q, later overwritten with attention output
  float* s_k   = ws + 2 * NE;
  float* s_v   = ws + 3 * NE;   // total ws use: 4*NE*4 = 117.4 MB

  k_conv<<<BB * CC, 128, 0, stream>>>(x, cw, cb, bg, bb, bm, bv, s_src);
  k_qkv<<<(BB * CC) / 32, 256, 0, stream>>>(s_src, wq, bq, wk, bk, wv, bvv,
                                            s_q, s_k, s_v);
  k_attn<<<BB * HH, 256, 0, stream>>>(s_q, s_k, s_v);
  k_out<<<(BB * CC) / 32, 256, 0, stream>>>(s_q, s_src, wo, bo, lg, lb, out);
}

// Round 2
// 230.258 us; speedup vs baseline: 2.3281x; 2.3281x over previous
//
#include <hip/hip_runtime.h>
#include <hip/hip_bf16.h>

#define BB 512
#define CC 112
#define DD 128
#define HH 8
#define HD 16
#define KK 8

typedef unsigned short u16;
typedef short short8 __attribute__((ext_vector_type(8)));
typedef float f32x4 __attribute__((ext_vector_type(4)));

#define MFMA16(a, b, c) __builtin_amdgcn_mfma_f32_16x16x32_bf16(a, b, c, 0, 0, 0)

__device__ inline u16 f2bf(float f) {
  union { float f; unsigned u; } v{f};
  unsigned r = (v.u + 0x7FFFu + ((v.u >> 16) & 1u)) >> 16;
  return (u16)r;
}

// ---------------------------------------------------------------------------
// K1: src = x + BN(GELU(dwconv(x))) ; also emits bf16 src and bf16 weights.
// ---------------------------------------------------------------------------
__global__ __launch_bounds__(128) void k_conv(
    const float* __restrict__ x, const float* __restrict__ cw,
    const float* __restrict__ cb, const float* __restrict__ bg,
    const float* __restrict__ bb_, const float* __restrict__ bm,
    const float* __restrict__ bv, float* __restrict__ src,
    u16* __restrict__ src_b,
    const float* __restrict__ wq, const float* __restrict__ wk,
    const float* __restrict__ wv, const float* __restrict__ wo,
    u16* __restrict__ w_b) {
  const int row = blockIdx.x;  // b*CC + c
  const int c = row % CC;
  const int d = threadIdx.x;
  __shared__ float sx[DD];
  const size_t base = (size_t)row * DD;
  const float xv = x[base + d];
  sx[d] = xv;
  // fold weight fp32->bf16 conversion into low blocks (65536 elems / 128)
  if (row < 512) {
    const int i = row * 128 + d;
    const int sel = i >> 14, off = i & 16383;
    const float* ws4 = (sel == 0) ? wq : (sel == 1) ? wk : (sel == 2) ? wv : wo;
    w_b[i] = f2bf(ws4[off]);
  }
  __syncthreads();
  float acc = 0.f;
#pragma unroll
  for (int k = 0; k < KK; ++k) {
    const int j = d - 3 + k;
    const float xn = (j >= 0 && j < DD) ? sx[j] : 0.f;
    acc = fmaf(xn, cw[c * KK + k], acc);
  }
  acc += cb[c];
  const float g = 0.5f * acc * (1.f + erff(acc * 0.70710678118654752440f));
  const float h = (g - bm[c]) * (bg[c] * rsqrtf(bv[c] + 1e-5f)) + bb_[c];
  const float s = xv + h;
  src[base + d] = s;
  src_b[base + d] = f2bf(s);
}

// ---------------------------------------------------------------------------
// K2: q/k/v = src @ W^T + b  via bf16 MFMA. Block=256 (4 waves), 128 rows.
// Wave owns 32 rows (2 M-tiles). Weights staged per-matrix in padded LDS.
// ---------------------------------------------------------------------------
__global__ __launch_bounds__(256) void k_qkv(
    const u16* __restrict__ src_b, const u16* __restrict__ w_b,
    const float* __restrict__ bq, const float* __restrict__ bk,
    const float* __restrict__ bv,
    u16* __restrict__ qb, u16* __restrict__ kb, u16* __restrict__ vb) {
  __shared__ u16 sw[128 * 136];  // padded rows: 136 u16 = 272 B (16B-aligned)
  const int t = threadIdx.x;
  const int wave = t >> 6, lane = t & 63;
  const int quad = lane >> 4, n = lane & 15;
  const int row0 = blockIdx.x * 128 + wave * 32;

  // A-frags: 2 M-tiles x 4 K-frags, direct from global bf16
  short8 A[2][4];
#pragma unroll
  for (int tile = 0; tile < 2; ++tile) {
    const size_t rbase = (size_t)(row0 + tile * 16 + n) * DD;
#pragma unroll
    for (int kf = 0; kf < 4; ++kf)
      A[tile][kf] = *(const short8*)(src_b + rbase + kf * 32 + quad * 8);
  }

  const float* const biases[3] = {bq, bk, bv};
  u16* const outs[3] = {qb, kb, vb};
  for (int m = 0; m < 3; ++m) {
    __syncthreads();  // protect sw reuse
    {
      const uint4* wsrc = (const uint4*)(w_b + m * 16384);
      for (int i = t; i < 2048; i += 256) {
        const int r = i >> 4, c = i & 15;
        *(uint4*)&sw[r * 136 + c * 8] = wsrc[r * 16 + c];
      }
    }
    __syncthreads();
    const float* __restrict__ bias = biases[m];
    u16* __restrict__ o = outs[m];
#pragma unroll
    for (int nt = 0; nt < 8; ++nt) {
      f32x4 acc0 = {0.f, 0.f, 0.f, 0.f};
      f32x4 acc1 = {0.f, 0.f, 0.f, 0.f};
#pragma unroll
      for (int kf = 0; kf < 4; ++kf) {
        const short8 Bf =
            *(const short8*)&sw[(nt * 16 + n) * 136 + kf * 32 + quad * 8];
        acc0 = MFMA16(A[0][kf], Bf, acc0);
        acc1 = MFMA16(A[1][kf], Bf, acc1);
      }
      const int col = nt * 16 + n;
      const float bcol = bias[col];
#pragma unroll
      for (int r = 0; r < 4; ++r) {
        o[(size_t)(row0 + quad * 4 + r) * DD + col] = f2bf(acc0[r] + bcol);
        o[(size_t)(row0 + 16 + quad * 4 + r) * DD + col] = f2bf(acc1[r] + bcol);
      }
    }
  }
}

// ---------------------------------------------------------------------------
// K3: attention, one wave per (b,h). Scores MFMA (e padded 16->32), softmax
// via 16-lane shfl reductions, P -> LDS bf16 (A-layout round trip), PV MFMA
// (K padded 112->128; P pad zeroed). Output bf16 to a_b.
// ---------------------------------------------------------------------------
__global__ __launch_bounds__(64) void k_attn(
    const u16* __restrict__ qb_, const u16* __restrict__ kb_,
    const u16* __restrict__ vb_, u16* __restrict__ ab_) {
  const int b = blockIdx.x >> 3;
  const int h = blockIdx.x & 7;
  const int lane = threadIdx.x;
  const int quad = lane >> 4, n = lane & 15;
  __shared__ u16 VT[16 * 136];  // V^T [e][key], keys padded to 128
  __shared__ u16 PL[16 * 136];  // P strip [query][key]
  const size_t hb = (size_t)b * CC * DD + h * HD;
  const u16* __restrict__ qh = qb_ + hb;
  const u16* __restrict__ kh = kb_ + hb;
  const u16* __restrict__ vh = vb_ + hb;

  // stage V^T (zero pad keys 112..127)
  for (int i = lane; i < 16 * 128; i += 64) {
    const int c = i >> 4, e = i & 15;
    VT[e * 136 + c] = (c < CC) ? vh[(size_t)c * DD + e] : (u16)0;
  }
  // zero P pad columns 112..127 (covers PV K-padding; done once)
  for (int i = lane; i < 256; i += 64) {
    const int r = i >> 4;
    PL[r * 136 + 112 + (i & 15)] = 0;
  }

  for (int mt = 0; mt < 7; ++mt) {
    __syncthreads();  // staging / previous strip's PV reads complete
    // Q A-frag: e = quad*8+j, real for quad<2, zero otherwise
    short8 Aq = {};
    if (quad < 2)
      Aq = *(const short8*)(qh + (size_t)(mt * 16 + n) * DD + quad * 8);
    float s[7][4];
#pragma unroll
    for (int jt = 0; jt < 7; ++jt) {
      short8 Bk = {};
      if (quad < 2)
        Bk = *(const short8*)(kh + (size_t)(jt * 16 + n) * DD + quad * 8);
      f32x4 acc = {0.f, 0.f, 0.f, 0.f};
      acc = MFMA16(Aq, Bk, acc);
#pragma unroll
      for (int r = 0; r < 4; ++r) s[jt][r] = acc[r] * 0.25f;  // SCALE
    }
    // row max across 112 keys: 7 local + 16-lane shfl tree
    float mx[4];
#pragma unroll
    for (int r = 0; r < 4; ++r) {
      float m = s[0][r];
#pragma unroll
      for (int jt = 1; jt < 7; ++jt) m = fmaxf(m, s[jt][r]);
      mx[r] = m;
    }
#pragma unroll
    for (int d = 1; d < 16; d <<= 1)
#pragma unroll
      for (int r = 0; r < 4; ++r) mx[r] = fmaxf(mx[r], __shfl_xor(mx[r], d));
    // exp, partial sums, write P (bf16) to LDS
    float sm[4] = {0.f, 0.f, 0.f, 0.f};
#pragma unroll
    for (int jt = 0; jt < 7; ++jt)
#pragma unroll
      for (int r = 0; r < 4; ++r) {
        const float p = __expf(s[jt][r] - mx[r]);
        sm[r] += p;
        PL[(quad * 4 + r) * 136 + jt * 16 + n] = f2bf(p);
      }
#pragma unroll
    for (int d = 1; d < 16; d <<= 1)
#pragma unroll
      for (int r = 0; r < 4; ++r) sm[r] += __shfl_xor(sm[r], d);
    __syncthreads();  // P visible to all quads
    // PV: O[16 x 16], K=128 (P pad is zero)
    f32x4 o = {0.f, 0.f, 0.f, 0.f};
#pragma unroll
    for (int f = 0; f < 4; ++f) {
      const short8 Ap = *(const short8*)&PL[n * 136 + f * 32 + quad * 8];
      const short8 Bv = *(const short8*)&VT[n * 136 + f * 32 + quad * 8];
      o = MFMA16(Ap, Bv, o);
    }
#pragma unroll
    for (int r = 0; r < 4; ++r) {
      const float val = o[r] * (1.f / sm[r]);
      ab_[hb + (size_t)(mt * 16 + quad * 4 + r) * DD + n] = f2bf(val);
    }
  }
}

// ---------------------------------------------------------------------------
// K4: out = LN(src + attn @ Wo^T + bo). MFMA + register LN (shfl reduce).
// Block=256 (4 waves), 64 rows; Wo staged in LDS.
// ---------------------------------------------------------------------------
__global__ __launch_bounds__(256) void k_out(
    const u16* __restrict__ a_b, const u16* __restrict__ w_bo,
    const float* __restrict__ bo, const float* __restrict__ src,
    const float* __restrict__ lg, const float* __restrict__ lb,
    float* __restrict__ out) {
  __shared__ u16 sw[128 * 136];
  const int t = threadIdx.x;
  const int wave = t >> 6, lane = t & 63;
  const int quad = lane >> 4, n = lane & 15;
  const int row0 = blockIdx.x * 64 + wave * 16;
  {
    const uint4* wsrc = (const uint4*)w_bo;
    for (int i = t; i < 2048; i += 256) {
      const int r = i >> 4, c = i & 15;
      *(uint4*)&sw[r * 136 + c * 8] = wsrc[r * 16 + c];
    }
  }
  short8 A[4];
  {
    const size_t rbase = (size_t)(row0 + n) * DD;
#pragma unroll
    for (int kf = 0; kf < 4; ++kf)
      A[kf] = *(const short8*)(a_b + rbase + kf * 32 + quad * 8);
  }
  __syncthreads();
  float v[8][4];
#pragma unroll
  for (int nt = 0; nt < 8; ++nt) {
    f32x4 acc = {0.f, 0.f, 0.f, 0.f};
#pragma unroll
    for (int kf = 0; kf < 4; ++kf) {
      const short8 Bf =
          *(const short8*)&sw[(nt * 16 + n) * 136 + kf * 32 + quad * 8];
      acc = MFMA16(A[kf], Bf, acc);
    }
    const int col = nt * 16 + n;
    const float bcol = bo[col];
#pragma unroll
    for (int r = 0; r < 4; ++r)
      v[nt][r] = acc[r] + bcol + src[(size_t)(row0 + quad * 4 + r) * DD + col];
  }
  // LayerNorm per row: row = quad*4+r, values spread over 16 lanes x 8 nt
  float sum[4] = {0.f, 0.f, 0.f, 0.f}, sq[4] = {0.f, 0.f, 0.f, 0.f};
#pragma unroll
  for (int nt = 0; nt < 8; ++nt)
#pragma unroll
    for (int r = 0; r < 4; ++r) {
      sum[r] += v[nt][r];
      sq[r] = fmaf(v[nt][r], v[nt][r], sq[r]);
    }
#pragma unroll
  for (int d = 1; d < 16; d <<= 1)
#pragma unroll
    for (int r = 0; r < 4; ++r) {
      sum[r] += __shfl_xor(sum[r], d);
      sq[r] += __shfl_xor(sq[r], d);
    }
  float mu[4], rs[4];
#pragma unroll
  for (int r = 0; r < 4; ++r) {
    mu[r] = sum[r] * (1.f / DD);
    const float var = sq[r] * (1.f / DD) - mu[r] * mu[r];
    rs[r] = rsqrtf(var + 1e-5f);
  }
#pragma unroll
  for (int nt = 0; nt < 8; ++nt) {
    const int col = nt * 16 + n;
    const float g = lg[col], be = lb[col];
#pragma unroll
    for (int r = 0; r < 4; ++r)
      out[(size_t)(row0 + quad * 4 + r) * DD + col] =
          (v[nt][r] - mu[r]) * rs[r] * g + be;
  }
}

extern "C" void kernel_launch(void* const* d_in, const int* in_sizes, int n_in,
                              void* d_out, int out_size, void* d_ws,
                              size_t ws_size, hipStream_t stream) {
  (void)in_sizes; (void)n_in; (void)out_size; (void)ws_size;
  const float* x   = (const float*)d_in[0];
  const float* cw  = (const float*)d_in[1];
  const float* cb  = (const float*)d_in[2];
  const float* bg  = (const float*)d_in[3];
  const float* bb  = (const float*)d_in[4];
  const float* bm  = (const float*)d_in[5];
  const float* bv  = (const float*)d_in[6];
  const float* wq  = (const float*)d_in[7];
  const float* bq  = (const float*)d_in[8];
  const float* wk  = (const float*)d_in[9];
  const float* bk  = (const float*)d_in[10];
  const float* wv  = (const float*)d_in[11];
  const float* bvv = (const float*)d_in[12];
  const float* wo  = (const float*)d_in[13];
  const float* bo  = (const float*)d_in[14];
  const float* lg  = (const float*)d_in[15];
  const float* lb  = (const float*)d_in[16];
  float* out = (float*)d_out;

  const size_t NE = (size_t)BB * CC * DD;  // 7,340,032
  float* s_src = (float*)d_ws;             // fp32 src (residual path)
  u16* ub = (u16*)((char*)d_ws + NE * 4);
  u16* src_b = ub;            // bf16 src
  u16* q_b   = ub + NE;
  u16* k_b   = ub + 2 * NE;
  u16* v_b   = ub + 3 * NE;
  u16* a_b   = ub + 4 * NE;   // attention output (bf16)
  u16* w_b   = ub + 5 * NE;   // 4 x 128x128 bf16 weights
  // total ws: 29.4 MB + 73.4 MB + 128 KB ~= 103 MB

  k_conv<<<BB * CC, 128, 0, stream>>>(x, cw, cb, bg, bb, bm, bv, s_src, src_b,
                                      wq, wk, wv, wo, w_b);
  k_qkv<<<(BB * CC) / 128, 256, 0, stream>>>(src_b, w_b, bq, bk, bvv,
                                             q_b, k_b, v_b);
  k_attn<<<BB * HH, 64, 0, stream>>>(q_b, k_b, v_b, a_b);
  k_out<<<(BB * CC) / 64, 256, 0, stream>>>(a_b, w_b + 3 * 16384, bo, s_src,
                                            lg, lb, out);
}

// Round 3
// 199.410 us; speedup vs baseline: 2.6882x; 1.1547x over previous
//
#include <hip/hip_runtime.h>
#include <hip/hip_bf16.h>

#define BB 512
#define CC 112
#define DD 128
#define HH 8
#define HD 16
#define KK 8

typedef unsigned short u16;
typedef short short8 __attribute__((ext_vector_type(8)));
typedef float f32x4 __attribute__((ext_vector_type(4)));

#define MFMA16(a, b, c) __builtin_amdgcn_mfma_f32_16x16x32_bf16(a, b, c, 0, 0, 0)

// LDS row pad: 140 u16 = 70 words; 70 % 32 = 6 -> 16 lanes at stride 6 hit 16
// distinct banks (n*6 mod 32 all distinct for n=0..15). 136 (stride 4) was the
// round-2 bank-conflict source (1.2M conflicts).
#define PAD 140

__device__ inline u16 f2bf(float f) {
  union { float f; unsigned u; } v{f};
  unsigned r = (v.u + 0x7FFFu + ((v.u >> 16) & 1u)) >> 16;
  return (u16)r;
}

// ---------------------------------------------------------------------------
// K1: src = x + BN(GELU(dwconv(x))); emits fp32 src, bf16 src, bf16 weights.
// ---------------------------------------------------------------------------
__global__ __launch_bounds__(128) void k_conv(
    const float* __restrict__ x, const float* __restrict__ cw,
    const float* __restrict__ cb, const float* __restrict__ bg,
    const float* __restrict__ bb_, const float* __restrict__ bm,
    const float* __restrict__ bv, float* __restrict__ src,
    u16* __restrict__ src_b,
    const float* __restrict__ wq, const float* __restrict__ wk,
    const float* __restrict__ wv, const float* __restrict__ wo,
    u16* __restrict__ w_b) {
  const int row = blockIdx.x;  // b*CC + c
  const int c = row % CC;
  const int d = threadIdx.x;
  __shared__ float sx[DD];
  const size_t base = (size_t)row * DD;
  const float xv = x[base + d];
  sx[d] = xv;
  if (row < 512) {  // fold 4x128x128 weight bf16 conversion into low blocks
    const int i = row * 128 + d;
    const int sel = i >> 14, off = i & 16383;
    const float* ws4 = (sel == 0) ? wq : (sel == 1) ? wk : (sel == 2) ? wv : wo;
    w_b[i] = f2bf(ws4[off]);
  }
  __syncthreads();
  float acc = 0.f;
#pragma unroll
  for (int k = 0; k < KK; ++k) {
    const int j = d - 3 + k;
    const float xn = (j >= 0 && j < DD) ? sx[j] : 0.f;
    acc = fmaf(xn, cw[c * KK + k], acc);
  }
  acc += cb[c];
  const float g = 0.5f * acc * (1.f + erff(acc * 0.70710678118654752440f));
  const float h = (g - bm[c]) * (bg[c] * rsqrtf(bv[c] + 1e-5f)) + bb_[c];
  const float s = xv + h;
  src[base + d] = s;
  src_b[base + d] = f2bf(s);
}

// ---------------------------------------------------------------------------
// K2: q/k/v = src @ W^T + b via bf16 MFMA, output HEAD-MAJOR [B,H,C,16].
// Block=256 (4 waves), 64 rows; wave owns 16 rows. Weights staged in LDS.
// ---------------------------------------------------------------------------
__global__ __launch_bounds__(256) void k_qkv(
    const u16* __restrict__ src_b, const u16* __restrict__ w_b,
    const float* __restrict__ bq, const float* __restrict__ bk,
    const float* __restrict__ bv,
    u16* __restrict__ qb, u16* __restrict__ kb, u16* __restrict__ vb) {
  __shared__ u16 sw[128 * PAD];
  const int t = threadIdx.x;
  const int wave = t >> 6, lane = t & 63;
  const int quad = lane >> 4, n = lane & 15;
  const int row0 = blockIdx.x * 64 + wave * 16;

  short8 A[4];
  {
    const size_t rbase = (size_t)(row0 + n) * DD;
#pragma unroll
    for (int kf = 0; kf < 4; ++kf)
      A[kf] = *(const short8*)(src_b + rbase + kf * 32 + quad * 8);
  }

  const float* const biases[3] = {bq, bk, bv};
  u16* const outs[3] = {qb, kb, vb};
  for (int m = 0; m < 3; ++m) {
    __syncthreads();  // protect sw reuse
    {
      const uint4* wsrc = (const uint4*)(w_b + m * 16384);
      for (int i = t; i < 2048; i += 256) {
        const int r = i >> 4, c = i & 15;
        *(uint4*)&sw[r * PAD + c * 8] = wsrc[r * 16 + c];
      }
    }
    __syncthreads();
    const float* __restrict__ bias = biases[m];
    u16* __restrict__ o = outs[m];
#pragma unroll
    for (int nt = 0; nt < 8; ++nt) {  // nt == head index h
      f32x4 acc = {0.f, 0.f, 0.f, 0.f};
#pragma unroll
      for (int kf = 0; kf < 4; ++kf) {
        const short8 Bf =
            *(const short8*)&sw[(nt * 16 + n) * PAD + kf * 32 + quad * 8];
        acc = MFMA16(A[kf], Bf, acc);
      }
      const float bcol = bias[nt * 16 + n];
#pragma unroll
      for (int r = 0; r < 4; ++r) {
        const int g = row0 + quad * 4 + r;        // global row
        const int b_ = g / CC, c_ = g - b_ * CC;  // batch, seq pos
        o[((size_t)(b_ * HH + nt) * CC + c_) * HD + n] = f2bf(acc[r] + bcol);
      }
    }
  }
}

// ---------------------------------------------------------------------------
// K3: attention, one wave per (b,h). q/k/v head-major (contiguous 3.5KB
// slices -> coalesced loads, L1-resident re-reads). Scores MFMA (e padded
// 16->32), softmax via 16-lane shfl, P->LDS bf16, PV MFMA (keys padded 128).
// Output row-major [B,C,D] bf16.
// ---------------------------------------------------------------------------
__global__ __launch_bounds__(64) void k_attn(
    const u16* __restrict__ qb_, const u16* __restrict__ kb_,
    const u16* __restrict__ vb_, u16* __restrict__ ab_) {
  const int bh = blockIdx.x;  // b*HH + h
  const int b = bh >> 3, h = bh & 7;
  const int lane = threadIdx.x;
  const int quad = lane >> 4, n = lane & 15;
  __shared__ u16 VT[HD * PAD];  // V^T [e][key], keys padded to 128
  __shared__ u16 PL[16 * PAD];  // P strip [query][key]
  const u16* __restrict__ qh = qb_ + (size_t)bh * CC * HD;
  const u16* __restrict__ kh = kb_ + (size_t)bh * CC * HD;
  const u16* __restrict__ vh = vb_ + (size_t)bh * CC * HD;
  u16* __restrict__ aout = ab_ + (size_t)b * CC * DD + h * HD;

  // stage V^T (coalesced read: lanes sweep e fastest; zero pad keys>=112)
  for (int i = lane; i < HD * 128; i += 64) {
    const int c = i >> 4, e = i & 15;
    VT[e * PAD + c] = (c < CC) ? vh[c * HD + e] : (u16)0;
  }
  // zero P pad columns 112..127 once (covers PV K-padding)
  for (int i = lane; i < 256; i += 64)
    PL[(i >> 4) * PAD + 112 + (i & 15)] = 0;

  for (int mt = 0; mt < 7; ++mt) {
    __syncthreads();  // staging done / previous strip's PV reads complete
    short8 Aq = {};
    if (quad < 2)  // e = quad*8+j real for e<16, zero-pad to K=32
      Aq = *(const short8*)(qh + (size_t)(mt * 16 + n) * HD + quad * 8);
    float s[7][4];
#pragma unroll
    for (int jt = 0; jt < 7; ++jt) {
      short8 Bk = {};
      if (quad < 2)
        Bk = *(const short8*)(kh + (size_t)(jt * 16 + n) * HD + quad * 8);
      f32x4 acc = {0.f, 0.f, 0.f, 0.f};
      acc = MFMA16(Aq, Bk, acc);
#pragma unroll
      for (int r = 0; r < 4; ++r) s[jt][r] = acc[r] * 0.25f;  // SCALE
    }
    float mx[4];
#pragma unroll
    for (int r = 0; r < 4; ++r) {
      float m = s[0][r];
#pragma unroll
      for (int jt = 1; jt < 7; ++jt) m = fmaxf(m, s[jt][r]);
      mx[r] = m;
    }
#pragma unroll
    for (int d = 1; d < 16; d <<= 1)
#pragma unroll
      for (int r = 0; r < 4; ++r) mx[r] = fmaxf(mx[r], __shfl_xor(mx[r], d));
    float sm[4] = {0.f, 0.f, 0.f, 0.f};
#pragma unroll
    for (int jt = 0; jt < 7; ++jt)
#pragma unroll
      for (int r = 0; r < 4; ++r) {
        const float p = __expf(s[jt][r] - mx[r]);
        sm[r] += p;
        PL[(quad * 4 + r) * PAD + jt * 16 + n] = f2bf(p);
      }
#pragma unroll
    for (int d = 1; d < 16; d <<= 1)
#pragma unroll
      for (int r = 0; r < 4; ++r) sm[r] += __shfl_xor(sm[r], d);
    __syncthreads();  // P visible across quads
    f32x4 o = {0.f, 0.f, 0.f, 0.f};
#pragma unroll
    for (int f = 0; f < 4; ++f) {
      const short8 Ap = *(const short8*)&PL[n * PAD + f * 32 + quad * 8];
      const short8 Bv = *(const short8*)&VT[n * PAD + f * 32 + quad * 8];
      o = MFMA16(Ap, Bv, o);
    }
#pragma unroll
    for (int r = 0; r < 4; ++r) {
      const float val = o[r] * (1.f / sm[r]);
      aout[(size_t)(mt * 16 + quad * 4 + r) * DD + n] = f2bf(val);
    }
  }
}

// ---------------------------------------------------------------------------
// K4: out = LN(src + attn @ Wo^T + bo). MFMA + register LN (shfl reduce).
// Block=256 (4 waves), 64 rows; Wo staged in LDS.
// ---------------------------------------------------------------------------
__global__ __launch_bounds__(256) void k_out(
    const u16* __restrict__ a_b, const u16* __restrict__ w_bo,
    const float* __restrict__ bo, const float* __restrict__ src,
    const float* __restrict__ lg, const float* __restrict__ lb,
    float* __restrict__ out) {
  __shared__ u16 sw[128 * PAD];
  const int t = threadIdx.x;
  const int wave = t >> 6, lane = t & 63;
  const int quad = lane >> 4, n = lane & 15;
  const int row0 = blockIdx.x * 64 + wave * 16;
  {
    const uint4* wsrc = (const uint4*)w_bo;
    for (int i = t; i < 2048; i += 256) {
      const int r = i >> 4, c = i & 15;
      *(uint4*)&sw[r * PAD + c * 8] = wsrc[r * 16 + c];
    }
  }
  short8 A[4];
  {
    const size_t rbase = (size_t)(row0 + n) * DD;
#pragma unroll
    for (int kf = 0; kf < 4; ++kf)
      A[kf] = *(const short8*)(a_b + rbase + kf * 32 + quad * 8);
  }
  __syncthreads();
  float v[8][4];
#pragma unroll
  for (int nt = 0; nt < 8; ++nt) {
    f32x4 acc = {0.f, 0.f, 0.f, 0.f};
#pragma unroll
    for (int kf = 0; kf < 4; ++kf) {
      const short8 Bf =
          *(const short8*)&sw[(nt * 16 + n) * PAD + kf * 32 + quad * 8];
      acc = MFMA16(A[kf], Bf, acc);
    }
    const int col = nt * 16 + n;
    const float bcol = bo[col];
#pragma unroll
    for (int r = 0; r < 4; ++r)
      v[nt][r] = acc[r] + bcol + src[(size_t)(row0 + quad * 4 + r) * DD + col];
  }
  float sum[4] = {0.f, 0.f, 0.f, 0.f}, sq[4] = {0.f, 0.f, 0.f, 0.f};
#pragma unroll
  for (int nt = 0; nt < 8; ++nt)
#pragma unroll
    for (int r = 0; r < 4; ++r) {
      sum[r] += v[nt][r];
      sq[r] = fmaf(v[nt][r], v[nt][r], sq[r]);
    }
#pragma unroll
  for (int d = 1; d < 16; d <<= 1)
#pragma unroll
    for (int r = 0; r < 4; ++r) {
      sum[r] += __shfl_xor(sum[r], d);
      sq[r] += __shfl_xor(sq[r], d);
    }
  float mu[4], rs[4];
#pragma unroll
  for (int r = 0; r < 4; ++r) {
    mu[r] = sum[r] * (1.f / DD);
    const float var = sq[r] * (1.f / DD) - mu[r] * mu[r];
    rs[r] = rsqrtf(var + 1e-5f);
  }
#pragma unroll
  for (int nt = 0; nt < 8; ++nt) {
    const int col = nt * 16 + n;
    const float g = lg[col], be = lb[col];
#pragma unroll
    for (int r = 0; r < 4; ++r)
      out[(size_t)(row0 + quad * 4 + r) * DD + col] =
          (v[nt][r] - mu[r]) * rs[r] * g + be;
  }
}

extern "C" void kernel_launch(void* const* d_in, const int* in_sizes, int n_in,
                              void* d_out, int out_size, void* d_ws,
                              size_t ws_size, hipStream_t stream) {
  (void)in_sizes; (void)n_in; (void)out_size; (void)ws_size;
  const float* x   = (const float*)d_in[0];
  const float* cw  = (const float*)d_in[1];
  const float* cb  = (const float*)d_in[2];
  const float* bg  = (const float*)d_in[3];
  const float* bb  = (const float*)d_in[4];
  const float* bm  = (const float*)d_in[5];
  const float* bv  = (const float*)d_in[6];
  const float* wq  = (const float*)d_in[7];
  const float* bq  = (const float*)d_in[8];
  const float* wk  = (const float*)d_in[9];
  const float* bk  = (const float*)d_in[10];
  const float* wv  = (const float*)d_in[11];
  const float* bvv = (const float*)d_in[12];
  const float* wo  = (const float*)d_in[13];
  const float* bo  = (const float*)d_in[14];
  const float* lg  = (const float*)d_in[15];
  const float* lb  = (const float*)d_in[16];
  float* out = (float*)d_out;

  const size_t NE = (size_t)BB * CC * DD;  // 7,340,032
  float* s_src = (float*)d_ws;             // fp32 src (residual path)
  u16* ub = (u16*)((char*)d_ws + NE * 4);
  u16* src_b = ub;            // bf16 src, row-major [B*C, D]
  u16* q_b   = ub + NE;       // head-major [B,H,C,16]
  u16* k_b   = ub + 2 * NE;   // head-major
  u16* v_b   = ub + 3 * NE;   // head-major
  u16* a_b   = ub + 4 * NE;   // attention out, row-major [B*C, D]
  u16* w_b   = ub + 5 * NE;   // 4 x 128x128 bf16 weights

  k_conv<<<BB * CC, 128, 0, stream>>>(x, cw, cb, bg, bb, bm, bv, s_src, src_b,
                                      wq, wk, wv, wo, w_b);
  k_qkv<<<(BB * CC) / 64, 256, 0, stream>>>(src_b, w_b, bq, bk, bvv,
                                            q_b, k_b, v_b);
  k_attn<<<BB * HH, 64, 0, stream>>>(q_b, k_b, v_b, a_b);
  k_out<<<(BB * CC) / 64, 256, 0, stream>>>(a_b, w_b + 3 * 16384, bo, s_src,
                                            lg, lb, out);
}

// Round 4
// 196.215 us; speedup vs baseline: 2.7320x; 1.0163x over previous
//
#include <hip/hip_runtime.h>
#include <hip/hip_bf16.h>

#define BB 512
#define CC 112
#define DD 128
#define HH 8
#define HD 16
#define KK 8

typedef unsigned short u16;
typedef short short8 __attribute__((ext_vector_type(8)));
typedef float f32x4 __attribute__((ext_vector_type(4)));

#define MFMA16(a, b, c) __builtin_amdgcn_mfma_f32_16x16x32_bf16(a, b, c, 0, 0, 0)

// LDS row pad: 140 u16 = 70 words; 70 % 32 = 6 -> 16 rows at stride 6 hit 16
// distinct banks. (136/stride-4 was the round-2 conflict source.)
#define PAD 140

__device__ inline u16 f2bf(float f) {
  union { float f; unsigned u; } v{f};
  unsigned r = (v.u + 0x7FFFu + ((v.u >> 16) & 1u)) >> 16;
  return (u16)r;
}

// ---------------------------------------------------------------------------
// K1: src = x + BN(GELU(dwconv(x))); emits fp32 src, bf16 src, bf16 weights.
// ---------------------------------------------------------------------------
__global__ __launch_bounds__(128) void k_conv(
    const float* __restrict__ x, const float* __restrict__ cw,
    const float* __restrict__ cb, const float* __restrict__ bg,
    const float* __restrict__ bb_, const float* __restrict__ bm,
    const float* __restrict__ bv, float* __restrict__ src,
    u16* __restrict__ src_b,
    const float* __restrict__ wq, const float* __restrict__ wk,
    const float* __restrict__ wv, const float* __restrict__ wo,
    u16* __restrict__ w_b) {
  const int row = blockIdx.x;  // b*CC + c
  const int c = row % CC;
  const int d = threadIdx.x;
  __shared__ float sx[DD];
  const size_t base = (size_t)row * DD;
  const float xv = x[base + d];
  sx[d] = xv;
  if (row < 512) {  // fold 4x128x128 weight bf16 conversion into low blocks
    const int i = row * 128 + d;
    const int sel = i >> 14, off = i & 16383;
    const float* ws4 = (sel == 0) ? wq : (sel == 1) ? wk : (sel == 2) ? wv : wo;
    w_b[i] = f2bf(ws4[off]);
  }
  __syncthreads();
  float acc = 0.f;
#pragma unroll
  for (int k = 0; k < KK; ++k) {
    const int j = d - 3 + k;
    const float xn = (j >= 0 && j < DD) ? sx[j] : 0.f;
    acc = fmaf(xn, cw[c * KK + k], acc);
  }
  acc += cb[c];
  const float g = 0.5f * acc * (1.f + erff(acc * 0.70710678118654752440f));
  const float h = (g - bm[c]) * (bg[c] * rsqrtf(bv[c] + 1e-5f)) + bb_[c];
  const float s = xv + h;
  src[base + d] = s;
  src_b[base + d] = f2bf(s);
}

// ---------------------------------------------------------------------------
// K2: q/k/v = src @ W^T + b via bf16 MFMA, output HEAD-MAJOR [B,H,C,16].
// Block=256 (4 waves), 64 rows. Store bases (div by 112) hoisted out of loops.
// ---------------------------------------------------------------------------
__global__ __launch_bounds__(256) void k_qkv(
    const u16* __restrict__ src_b, const u16* __restrict__ w_b,
    const float* __restrict__ bq, const float* __restrict__ bk,
    const float* __restrict__ bv,
    u16* __restrict__ qb, u16* __restrict__ kb, u16* __restrict__ vb) {
  __shared__ u16 sw[128 * PAD];
  const int t = threadIdx.x;
  const int wave = t >> 6, lane = t & 63;
  const int quad = lane >> 4, n = lane & 15;
  const int row0 = blockIdx.x * 64 + wave * 16;

  short8 A[4];
  {
    const size_t rbase = (size_t)(row0 + n) * DD;
#pragma unroll
    for (int kf = 0; kf < 4; ++kf)
      A[kf] = *(const short8*)(src_b + rbase + kf * 32 + quad * 8);
  }
  // hoisted per-output-row store bases (head-major [B,H,C,16])
  size_t base_r[4];
#pragma unroll
  for (int r = 0; r < 4; ++r) {
    const int g = row0 + quad * 4 + r;
    const int b_ = g / CC, c_ = g - b_ * CC;
    base_r[r] = ((size_t)b_ * HH * CC + c_) * HD + n;
  }

  const float* const biases[3] = {bq, bk, bv};
  u16* const outs[3] = {qb, kb, vb};
  for (int m = 0; m < 3; ++m) {
    __syncthreads();  // protect sw reuse
    {
      const uint4* wsrc = (const uint4*)(w_b + m * 16384);
      for (int i = t; i < 2048; i += 256) {
        const int r = i >> 4, c = i & 15;
        *(uint4*)&sw[r * PAD + c * 8] = wsrc[r * 16 + c];
      }
    }
    __syncthreads();
    const float* __restrict__ bias = biases[m];
    u16* __restrict__ o = outs[m];
#pragma unroll
    for (int nt = 0; nt < 8; ++nt) {  // nt == head index
      f32x4 acc = {0.f, 0.f, 0.f, 0.f};
#pragma unroll
      for (int kf = 0; kf < 4; ++kf) {
        const short8 Bf =
            *(const short8*)&sw[(nt * 16 + n) * PAD + kf * 32 + quad * 8];
        acc = MFMA16(A[kf], Bf, acc);
      }
      const float bcol = bias[nt * 16 + n];
      const size_t hoff = (size_t)nt * CC * HD;
#pragma unroll
      for (int r = 0; r < 4; ++r)
        o[base_r[r] + hoff] = f2bf(acc[r] + bcol);
    }
  }
}

// ---------------------------------------------------------------------------
// K3: attention. Block = 448 threads = 7 waves, one per 16-query strip of one
// (b,h). Each wave: scores MFMA (e padded 16->32) -> softmax (16-lane shfl)
// -> P into PRIVATE LDS strip -> PV MFMA (keys padded to 128). Only one block
// barrier (V^T staging). Critical path = 1 strip (was 7).
// ---------------------------------------------------------------------------
__global__ __launch_bounds__(448) void k_attn(
    const u16* __restrict__ qb_, const u16* __restrict__ kb_,
    const u16* __restrict__ vb_, u16* __restrict__ ab_) {
  const int bh = blockIdx.x;  // b*HH + h
  const int b = bh >> 3, h = bh & 7;
  const int t = threadIdx.x;
  const int wave = t >> 6;  // == mt strip index, 0..6
  const int lane = t & 63;
  const int quad = lane >> 4, n = lane & 15;
  __shared__ u16 VT[HD * PAD];      // V^T [e][key], keys zero-padded to 128
  __shared__ u16 PL[7 * 16 * PAD];  // per-wave private P strips
  const u16* __restrict__ qh = qb_ + (size_t)bh * CC * HD;
  const u16* __restrict__ kh = kb_ + (size_t)bh * CC * HD;
  const u16* __restrict__ vh = vb_ + (size_t)bh * CC * HD;
  u16* __restrict__ aout = ab_ + (size_t)b * CC * DD + h * HD;

  // stage V^T cooperatively (coalesced: lanes sweep e fastest)
  for (int i = t; i < HD * 128; i += 448) {
    const int c = i >> 4, e = i & 15;
    VT[e * PAD + c] = (c < CC) ? vh[c * HD + e] : (u16)0;
  }
  u16* __restrict__ PW = PL + wave * 16 * PAD;
  // zero own strip's pad columns 112..127 (covers PV K-padding; wave-local)
  for (int i = lane; i < 256; i += 64)
    PW[(i >> 4) * PAD + 112 + (i & 15)] = 0;
  __syncthreads();  // VT visible to all waves

  const int mt = wave;
  short8 Aq = {};
  if (quad < 2)  // e = quad*8+j real for e<16, zero-pad K 16->32
    Aq = *(const short8*)(qh + (size_t)(mt * 16 + n) * HD + quad * 8);
  float s[7][4];
#pragma unroll
  for (int jt = 0; jt < 7; ++jt) {
    short8 Bk = {};
    if (quad < 2)
      Bk = *(const short8*)(kh + (size_t)(jt * 16 + n) * HD + quad * 8);
    f32x4 acc = {0.f, 0.f, 0.f, 0.f};
    acc = MFMA16(Aq, Bk, acc);
#pragma unroll
    for (int r = 0; r < 4; ++r) s[jt][r] = acc[r] * 0.25f;  // SCALE
  }
  float mx[4];
#pragma unroll
  for (int r = 0; r < 4; ++r) {
    float m = s[0][r];
#pragma unroll
    for (int jt = 1; jt < 7; ++jt) m = fmaxf(m, s[jt][r]);
    mx[r] = m;
  }
#pragma unroll
  for (int d = 1; d < 16; d <<= 1)
#pragma unroll
    for (int r = 0; r < 4; ++r) mx[r] = fmaxf(mx[r], __shfl_xor(mx[r], d));
  float sm[4] = {0.f, 0.f, 0.f, 0.f};
#pragma unroll
  for (int jt = 0; jt < 7; ++jt)
#pragma unroll
    for (int r = 0; r < 4; ++r) {
      const float p = __expf(s[jt][r] - mx[r]);
      sm[r] += p;
      PW[(quad * 4 + r) * PAD + jt * 16 + n] = f2bf(p);
    }
#pragma unroll
  for (int d = 1; d < 16; d <<= 1)
#pragma unroll
    for (int r = 0; r < 4; ++r) sm[r] += __shfl_xor(sm[r], d);
  __threadfence_block();  // order P writes before cross-lane LDS reads (wave-local)
  f32x4 o = {0.f, 0.f, 0.f, 0.f};
#pragma unroll
  for (int f = 0; f < 4; ++f) {
    const short8 Ap = *(const short8*)&PW[n * PAD + f * 32 + quad * 8];
    const short8 Bv = *(const short8*)&VT[n * PAD + f * 32 + quad * 8];
    o = MFMA16(Ap, Bv, o);
  }
#pragma unroll
  for (int r = 0; r < 4; ++r) {
    const float val = o[r] * (1.f / sm[r]);
    aout[(size_t)(mt * 16 + quad * 4 + r) * DD + n] = f2bf(val);
  }
}

// ---------------------------------------------------------------------------
// K4: out = LN(src + attn @ Wo^T + bo). MFMA + register LN (shfl reduce).
// Block=256 (4 waves), 64 rows; Wo staged in LDS.
// ---------------------------------------------------------------------------
__global__ __launch_bounds__(256) void k_out(
    const u16* __restrict__ a_b, const u16* __restrict__ w_bo,
    const float* __restrict__ bo, const float* __restrict__ src,
    const float* __restrict__ lg, const float* __restrict__ lb,
    float* __restrict__ out) {
  __shared__ u16 sw[128 * PAD];
  const int t = threadIdx.x;
  const int wave = t >> 6, lane = t & 63;
  const int quad = lane >> 4, n = lane & 15;
  const int row0 = blockIdx.x * 64 + wave * 16;
  {
    const uint4* wsrc = (const uint4*)w_bo;
    for (int i = t; i < 2048; i += 256) {
      const int r = i >> 4, c = i & 15;
      *(uint4*)&sw[r * PAD + c * 8] = wsrc[r * 16 + c];
    }
  }
  short8 A[4];
  {
    const size_t rbase = (size_t)(row0 + n) * DD;
#pragma unroll
    for (int kf = 0; kf < 4; ++kf)
      A[kf] = *(const short8*)(a_b + rbase + kf * 32 + quad * 8);
  }
  __syncthreads();
  float v[8][4];
#pragma unroll
  for (int nt = 0; nt < 8; ++nt) {
    f32x4 acc = {0.f, 0.f, 0.f, 0.f};
#pragma unroll
    for (int kf = 0; kf < 4; ++kf) {
      const short8 Bf =
          *(const short8*)&sw[(nt * 16 + n) * PAD + kf * 32 + quad * 8];
      acc = MFMA16(A[kf], Bf, acc);
    }
    const int col = nt * 16 + n;
    const float bcol = bo[col];
#pragma unroll
    for (int r = 0; r < 4; ++r)
      v[nt][r] = acc[r] + bcol + src[(size_t)(row0 + quad * 4 + r) * DD + col];
  }
  float sum[4] = {0.f, 0.f, 0.f, 0.f}, sq[4] = {0.f, 0.f, 0.f, 0.f};
#pragma unroll
  for (int nt = 0; nt < 8; ++nt)
#pragma unroll
    for (int r = 0; r < 4; ++r) {
      sum[r] += v[nt][r];
      sq[r] = fmaf(v[nt][r], v[nt][r], sq[r]);
    }
#pragma unroll
  for (int d = 1; d < 16; d <<= 1)
#pragma unroll
    for (int r = 0; r < 4; ++r) {
      sum[r] += __shfl_xor(sum[r], d);
      sq[r] += __shfl_xor(sq[r], d);
    }
  float mu[4], rs[4];
#pragma unroll
  for (int r = 0; r < 4; ++r) {
    mu[r] = sum[r] * (1.f / DD);
    const float var = sq[r] * (1.f / DD) - mu[r] * mu[r];
    rs[r] = rsqrtf(var + 1e-5f);
  }
#pragma unroll
  for (int nt = 0; nt < 8; ++nt) {
    const int col = nt * 16 + n;
    const float g = lg[col], be = lb[col];
#pragma unroll
    for (int r = 0; r < 4; ++r)
      out[(size_t)(row0 + quad * 4 + r) * DD + col] =
          (v[nt][r] - mu[r]) * rs[r] * g + be;
  }
}

extern "C" void kernel_launch(void* const* d_in, const int* in_sizes, int n_in,
                              void* d_out, int out_size, void* d_ws,
                              size_t ws_size, hipStream_t stream) {
  (void)in_sizes; (void)n_in; (void)out_size; (void)ws_size;
  const float* x   = (const float*)d_in[0];
  const float* cw  = (const float*)d_in[1];
  const float* cb  = (const float*)d_in[2];
  const float* bg  = (const float*)d_in[3];
  const float* bb  = (const float*)d_in[4];
  const float* bm  = (const float*)d_in[5];
  const float* bv  = (const float*)d_in[6];
  const float* wq  = (const float*)d_in[7];
  const float* bq  = (const float*)d_in[8];
  const float* wk  = (const float*)d_in[9];
  const float* bk  = (const float*)d_in[10];
  const float* wv  = (const float*)d_in[11];
  const float* bvv = (const float*)d_in[12];
  const float* wo  = (const float*)d_in[13];
  const float* bo  = (const float*)d_in[14];
  const float* lg  = (const float*)d_in[15];
  const float* lb  = (const float*)d_in[16];
  float* out = (float*)d_out;

  const size_t NE = (size_t)BB * CC * DD;  // 7,340,032
  float* s_src = (float*)d_ws;             // fp32 src (residual path)
  u16* ub = (u16*)((char*)d_ws + NE * 4);
  u16* src_b = ub;            // bf16 src, row-major [B*C, D]
  u16* q_b   = ub + NE;       // head-major [B,H,C,16]
  u16* k_b   = ub + 2 * NE;   // head-major
  u16* v_b   = ub + 3 * NE;   // head-major
  u16* a_b   = ub + 4 * NE;   // attention out, row-major [B*C, D]
  u16* w_b   = ub + 5 * NE;   // 4 x 128x128 bf16 weights

  k_conv<<<BB * CC, 128, 0, stream>>>(x, cw, cb, bg, bb, bm, bv, s_src, src_b,
                                      wq, wk, wv, wo, w_b);
  k_qkv<<<(BB * CC) / 64, 256, 0, stream>>>(src_b, w_b, bq, bk, bvv,
                                            q_b, k_b, v_b);
  k_attn<<<BB * HH, 448, 0, stream>>>(q_b, k_b, v_b, a_b);
  k_out<<<(BB * CC) / 64, 256, 0, stream>>>(a_b, w_b + 3 * 16384, bo, s_src,
                                            lg, lb, out);
}

// Round 5
// 186.195 us; speedup vs baseline: 2.8790x; 1.0538x over previous
//
#include <hip/hip_runtime.h>
#include <hip/hip_bf16.h>

#define BB 512
#define CC 112
#define DD 128
#define HH 8
#define HD 16
#define KK 8

typedef unsigned short u16;
typedef short short8 __attribute__((ext_vector_type(8)));
typedef float f32x4 __attribute__((ext_vector_type(4)));
typedef float f32x16 __attribute__((ext_vector_type(16)));

#define MFMA16(a, b, c) __builtin_amdgcn_mfma_f32_16x16x32_bf16(a, b, c, 0, 0, 0)
#define MFMA32(a, b, c) __builtin_amdgcn_mfma_f32_32x32x16_bf16(a, b, c, 0, 0, 0)

// LDS row stride 136 u16 = 272 B: 16B-aligned rows (true b128), bank stride
// 4 words -> 2-way alias on 16-row arrays (free, m136), 4-way on 32-row PL
// (1.58x on 7 reads/lane -- negligible).
#define PAD 136

__device__ inline u16 f2bf(float f) {
  union { float f; unsigned u; } v{f};
  unsigned r = (v.u + 0x7FFFu + ((v.u >> 16) & 1u)) >> 16;
  return (u16)r;
}
__device__ inline float bf2f(u16 u) {
  union { unsigned u; float f; } v;
  v.u = ((unsigned)u) << 16;
  return v.f;
}
__device__ inline unsigned pk2(float a, float b) {
  __hip_bfloat162 h = __float22bfloat162_rn(float2{a, b});
  union { __hip_bfloat162 h; unsigned u; } v{h};
  return v.u;
}

// ---------------------------------------------------------------------------
// K1: fused conv+GELU+BN+residual+QKV. Block=256 (4 waves), 64 token rows.
// Each lane conv-computes exactly its own MFMA A-frag elements (cols
// kf*32+quad*8+j of row n) -> A-frags assembled in registers, no LDS/barrier
// for the conv->GEMM handoff. Weights converted fp32->bf16 during staging.
// q/k stored head-major [B,H,C,16]; v stored TRANSPOSED [B,H,16,C] for attn.
// ---------------------------------------------------------------------------
__global__ __launch_bounds__(256) void k_cqkv(
    const float* __restrict__ x, const float* __restrict__ cw,
    const float* __restrict__ cb, const float* __restrict__ bg,
    const float* __restrict__ bb_, const float* __restrict__ bm,
    const float* __restrict__ bv,
    const float* __restrict__ wq, const float* __restrict__ bq,
    const float* __restrict__ wk, const float* __restrict__ bk,
    const float* __restrict__ wv, const float* __restrict__ bvv,
    u16* __restrict__ src_b, u16* __restrict__ qb, u16* __restrict__ kb,
    u16* __restrict__ vtb) {
  __shared__ u16 sw[128 * PAD];
  const int t = threadIdx.x;
  const int wave = t >> 6, lane = t & 63;
  const int quad = lane >> 4, n = lane & 15;
  const int row_g = blockIdx.x * 64 + wave * 16 + n;  // this lane's token row
  const int ch = row_g % CC;                          // conv channel

  // conv/BN per-channel params
  const float4 w0 = *(const float4*)(cw + ch * KK);
  const float4 w1 = *(const float4*)(cw + ch * KK + 4);
  const float cbv = cb[ch];
  const float bscale = bg[ch] * rsqrtf(bv[ch] + 1e-5f);
  const float bmv = bm[ch], bbv = bb_[ch];

  const float* __restrict__ xr = x + (size_t)row_g * DD;
  u16* __restrict__ sbr = src_b + (size_t)row_g * DD;

  short8 A[4];
#pragma unroll
  for (int kf = 0; kf < 4; ++kf) {
    const int c0 = kf * 32 + quad * 8;  // 8 outputs c0..c0+7
    float in[16];                       // cols c0-4 .. c0+11
#pragma unroll
    for (int f = 0; f < 4; ++f) {
      const int fi = (c0 >> 2) - 1 + f;
      float4 vv = {0.f, 0.f, 0.f, 0.f};
      if (fi >= 0 && fi < 32) vv = ((const float4*)xr)[fi];
      in[f * 4 + 0] = vv.x; in[f * 4 + 1] = vv.y;
      in[f * 4 + 2] = vv.z; in[f * 4 + 3] = vv.w;
    }
    u16 ob[8];
#pragma unroll
    for (int i = 0; i < 8; ++i) {
      float a = 0.f;
      a = fmaf(in[i + 1], w0.x, a);
      a = fmaf(in[i + 2], w0.y, a);
      a = fmaf(in[i + 3], w0.z, a);
      a = fmaf(in[i + 4], w0.w, a);
      a = fmaf(in[i + 5], w1.x, a);
      a = fmaf(in[i + 6], w1.y, a);
      a = fmaf(in[i + 7], w1.z, a);
      a = fmaf(in[i + 8], w1.w, a);
      a += cbv;
      const float g = 0.5f * a * (1.f + erff(a * 0.70710678118654752440f));
      const float s = in[i + 4] + (g - bmv) * bscale + bbv;  // x + BN(GELU)
      ob[i] = f2bf(s);
    }
    A[kf] = *(short8*)ob;
    *(short8*)(sbr + c0) = A[kf];  // bf16 residual for k_out
  }

  // hoisted store bases for the MFMA C-layout rows (token = row0w+quad*4+r)
  const int row0w = blockIdx.x * 64 + wave * 16;
  int qk_base[4], vt_base[4];
#pragma unroll
  for (int r = 0; r < 4; ++r) {
    const int g = row0w + quad * 4 + r;
    const int b_ = g / CC, c_ = g - b_ * CC;
    qk_base[r] = (b_ * (HH * CC) + c_) * HD + n;  // + h*CC*HD per head
    vt_base[r] = b_ * (HH * HD * CC) + n * CC + c_;  // + h*HD*CC per head
  }

  const float* const wmats[3] = {wq, wk, wv};
  const float* const biases[3] = {bq, bk, bvv};
  for (int m = 0; m < 3; ++m) {
    __syncthreads();  // protect sw reuse
    {
      const float4* wsrc = (const float4*)wmats[m];
      for (int i = t; i < 4096; i += 256) {  // 128x128 fp32 -> bf16 LDS
        const int r = i >> 5, c4 = (i & 31) * 4;
        const float4 vv = wsrc[i];
        *(uint2*)&sw[r * PAD + c4] = uint2{pk2(vv.x, vv.y), pk2(vv.z, vv.w)};
      }
    }
    __syncthreads();
    const float* __restrict__ bias = biases[m];
#pragma unroll
    for (int nt = 0; nt < 8; ++nt) {  // nt == head index
      f32x4 acc = {0.f, 0.f, 0.f, 0.f};
#pragma unroll
      for (int kf = 0; kf < 4; ++kf) {
        const short8 Bf =
            *(const short8*)&sw[(nt * 16 + n) * PAD + kf * 32 + quad * 8];
        acc = MFMA16(A[kf], Bf, acc);
      }
      const float bcol = bias[nt * 16 + n];
      if (m < 2) {
        u16* __restrict__ o = (m == 0) ? qb : kb;
        const int hoff = nt * (CC * HD);
#pragma unroll
        for (int r = 0; r < 4; ++r)
          o[qk_base[r] + hoff] = f2bf(acc[r] + bcol);
      } else {
        const int hoff = nt * (HD * CC);
#pragma unroll
        for (int r = 0; r < 4; ++r)
          vtb[vt_base[r] + hoff] = f2bf(acc[r] + bcol);
      }
    }
  }
}

// ---------------------------------------------------------------------------
// K2: attention. Block=256 (4 waves) per (b,h); wave owns 32 queries via
// mfma_32x32x16 (K=16=HD exact). Scores computed transposed (S^T = K*Q^T) so
// softmax is reg-local + ONE shfl_xor(32). P normalized in-registers, packed
// (cvt_pk_bf16) and written as b64 runs of 4 keys to private LDS; PV reads
// contiguous short8 A-frags. 7 K-tiles of 16 = 112 keys exact (no pad).
// ---------------------------------------------------------------------------
__global__ __launch_bounds__(256) void k_attn(
    const u16* __restrict__ qb_, const u16* __restrict__ kb_,
    const u16* __restrict__ vtb_, u16* __restrict__ ab_) {
  const int bh = blockIdx.x;  // b*HH + h
  const int b = bh >> 3, h = bh & 7;
  const int t = threadIdx.x;
  const int wave = t >> 6;          // query tile (32 queries)
  const int lane = t & 63;
  const int lo = lane & 31;
  const int hi8 = (lane >> 5) * 8;  // k-chunk offset within K=16
  __shared__ u16 VT[HD * PAD];       // V^T [e][key]
  __shared__ u16 PL[4 * 32 * PAD];   // per-wave private P [q][key]
  const u16* __restrict__ qh = qb_ + (size_t)bh * (CC * HD);
  const u16* __restrict__ kh = kb_ + (size_t)bh * (CC * HD);
  const u16* __restrict__ vth = vtb_ + (size_t)bh * (HD * CC);
  u16* __restrict__ aout = ab_ + (size_t)b * (CC * DD) + h * HD;

  // stage V^T: producer already transposed -> 224 vector loads
  for (int i = t; i < 224; i += 256) {
    const int e = i / 14, c0 = (i - e * 14) * 8;
    *(short8*)&VT[e * PAD + c0] = *(const short8*)(vth + e * CC + c0);
  }
  __syncthreads();

  u16* __restrict__ PW = PL + wave * (32 * PAD);
  const int qt0 = wave * 32;

  // scores S^T = K * Q^T : D[key][query], 4 key tiles of 32
  short8 Bq = {};
  if (qt0 + lo < CC)
    Bq = *(const short8*)(qh + (qt0 + lo) * HD + hi8);
  f32x16 sa[4];
#pragma unroll
  for (int mt = 0; mt < 4; ++mt) {
    short8 Ak = {};
    const int key = mt * 32 + lo;
    if (key < CC) Ak = *(const short8*)(kh + key * HD + hi8);
    f32x16 z = {};
    sa[mt] = MFMA32(Ak, Bq, z);
  }
  // lane holds S^T[key = 32*mt + (r&3)+8*(r>>2)+4*(lane>>5)][query=qt0+lo].
  // Real keys: mt<3 all regs; mt=3 regs 0..7 (keys 96..111).
  const float C1 = 0.25f * 1.44269504088896341f;  // SCALE * log2(e)
  float mx = -1e30f;
#pragma unroll
  for (int mt = 0; mt < 4; ++mt) {
    const int rmax = (mt == 3) ? 8 : 16;
#pragma unroll
    for (int r = 0; r < 16; ++r)
      if (r < rmax) mx = fmaxf(mx, sa[mt][r]);
  }
  mx = fmaxf(mx, __shfl_xor(mx, 32));
  const float mxc = mx * C1;
  float sum = 0.f;
#pragma unroll
  for (int mt = 0; mt < 4; ++mt) {
    const int rmax = (mt == 3) ? 8 : 16;
#pragma unroll
    for (int r = 0; r < 16; ++r)
      if (r < rmax) {
        const float p = exp2f(fmaf(sa[mt][r], C1, -mxc));
        sa[mt][r] = p;
        sum += p;
      }
  }
  sum += __shfl_xor(sum, 32);
  const float rinv = 1.f / sum;
  // normalized P -> LDS as b64 runs of 4 consecutive keys
#pragma unroll
  for (int mt = 0; mt < 4; ++mt) {
    const int nruns = (mt == 3) ? 2 : 4;
#pragma unroll
    for (int run = 0; run < 4; ++run)
      if (run < nruns) {
        const int k0 = mt * 32 + run * 8 + (lane >> 5) * 4;
        const unsigned u0 =
            pk2(sa[mt][4 * run + 0] * rinv, sa[mt][4 * run + 1] * rinv);
        const unsigned u1 =
            pk2(sa[mt][4 * run + 2] * rinv, sa[mt][4 * run + 3] * rinv);
        *(uint2*)&PW[lo * PAD + k0] = uint2{u0, u1};
      }
  }
  __threadfence_block();  // order wave-local P writes before LDS reads
  // PV: O[32q][16e] = P*V, 7 K-tiles of 16 keys (112 exact)
  f32x16 oacc = {};
#pragma unroll
  for (int kt = 0; kt < 7; ++kt) {
    const short8 Ap = *(const short8*)&PW[lo * PAD + kt * 16 + hi8];
    short8 Bv = {};
    if (lo < HD) Bv = *(const short8*)&VT[lo * PAD + kt * 16 + hi8];
    oacc = MFMA32(Ap, Bv, oacc);
  }
  // D[row=query-in-tile][col=e=lo]; store only real e and real queries
  if (lo < HD) {
#pragma unroll
    for (int r = 0; r < 16; ++r) {
      const int qrow = qt0 + (r & 3) + 8 * (r >> 2) + 4 * (lane >> 5);
      if (qrow < CC) aout[(size_t)qrow * DD + lo] = f2bf(oacc[r]);
    }
  }
}

// ---------------------------------------------------------------------------
// K3: out = LN(src + attn @ Wo^T + bo). MFMA + register LN (shfl reduce).
// Block=256 (4 waves), 64 rows; Wo converted fp32->bf16 during staging;
// residual src read as bf16.
// ---------------------------------------------------------------------------
__global__ __launch_bounds__(256) void k_out(
    const u16* __restrict__ a_b, const float* __restrict__ wo,
    const float* __restrict__ bo, const u16* __restrict__ src_b,
    const float* __restrict__ lg, const float* __restrict__ lb,
    float* __restrict__ out) {
  __shared__ u16 sw[128 * PAD];
  const int t = threadIdx.x;
  const int wave = t >> 6, lane = t & 63;
  const int quad = lane >> 4, n = lane & 15;
  const int row0 = blockIdx.x * 64 + wave * 16;
  {
    const float4* wsrc = (const float4*)wo;
    for (int i = t; i < 4096; i += 256) {
      const int r = i >> 5, c4 = (i & 31) * 4;
      const float4 vv = wsrc[i];
      *(uint2*)&sw[r * PAD + c4] = uint2{pk2(vv.x, vv.y), pk2(vv.z, vv.w)};
    }
  }
  short8 A[4];
  {
    const size_t rbase = (size_t)(row0 + n) * DD;
#pragma unroll
    for (int kf = 0; kf < 4; ++kf)
      A[kf] = *(const short8*)(a_b + rbase + kf * 32 + quad * 8);
  }
  __syncthreads();
  float v[8][4];
#pragma unroll
  for (int nt = 0; nt < 8; ++nt) {
    f32x4 acc = {0.f, 0.f, 0.f, 0.f};
#pragma unroll
    for (int kf = 0; kf < 4; ++kf) {
      const short8 Bf =
          *(const short8*)&sw[(nt * 16 + n) * PAD + kf * 32 + quad * 8];
      acc = MFMA16(A[kf], Bf, acc);
    }
    const int col = nt * 16 + n;
    const float bcol = bo[col];
#pragma unroll
    for (int r = 0; r < 4; ++r)
      v[nt][r] = acc[r] + bcol +
                 bf2f(src_b[(size_t)(row0 + quad * 4 + r) * DD + col]);
  }
  float sum[4] = {0.f, 0.f, 0.f, 0.f}, sq[4] = {0.f, 0.f, 0.f, 0.f};
#pragma unroll
  for (int nt = 0; nt < 8; ++nt)
#pragma unroll
    for (int r = 0; r < 4; ++r) {
      sum[r] += v[nt][r];
      sq[r] = fmaf(v[nt][r], v[nt][r], sq[r]);
    }
#pragma unroll
  for (int d = 1; d < 16; d <<= 1)
#pragma unroll
    for (int r = 0; r < 4; ++r) {
      sum[r] += __shfl_xor(sum[r], d);
      sq[r] += __shfl_xor(sq[r], d);
    }
  float mu[4], rs[4];
#pragma unroll
  for (int r = 0; r < 4; ++r) {
    mu[r] = sum[r] * (1.f / DD);
    const float var = sq[r] * (1.f / DD) - mu[r] * mu[r];
    rs[r] = rsqrtf(var + 1e-5f);
  }
#pragma unroll
  for (int nt = 0; nt < 8; ++nt) {
    const int col = nt * 16 + n;
    const float g = lg[col], be = lb[col];
#pragma unroll
    for (int r = 0; r < 4; ++r)
      out[(size_t)(row0 + quad * 4 + r) * DD + col] =
          (v[nt][r] - mu[r]) * rs[r] * g + be;
  }
}

extern "C" void kernel_launch(void* const* d_in, const int* in_sizes, int n_in,
                              void* d_out, int out_size, void* d_ws,
                              size_t ws_size, hipStream_t stream) {
  (void)in_sizes; (void)n_in; (void)out_size; (void)ws_size;
  const float* x   = (const float*)d_in[0];
  const float* cw  = (const float*)d_in[1];
  const float* cb  = (const float*)d_in[2];
  const float* bg  = (const float*)d_in[3];
  const float* bb  = (const float*)d_in[4];
  const float* bm  = (const float*)d_in[5];
  const float* bv  = (const float*)d_in[6];
  const float* wq  = (const float*)d_in[7];
  const float* bq  = (const float*)d_in[8];
  const float* wk  = (const float*)d_in[9];
  const float* bk  = (const float*)d_in[10];
  const float* wv  = (const float*)d_in[11];
  const float* bvv = (const float*)d_in[12];
  const float* wo  = (const float*)d_in[13];
  const float* bo  = (const float*)d_in[14];
  const float* lg  = (const float*)d_in[15];
  const float* lb  = (const float*)d_in[16];
  float* out = (float*)d_out;

  const size_t NE = (size_t)BB * CC * DD;  // 7,340,032
  u16* ub = (u16*)d_ws;
  u16* src_b = ub;            // bf16 src, row-major [B*C, D]
  u16* q_b   = ub + NE;       // head-major [B,H,C,16]
  u16* k_b   = ub + 2 * NE;   // head-major [B,H,C,16]
  u16* vt_b  = ub + 3 * NE;   // TRANSPOSED head-major [B,H,16,C]
  u16* a_b   = ub + 4 * NE;   // attention out, row-major [B*C, D]
  // ws use: 5*NE*2 = 73.4 MB

  k_cqkv<<<(BB * CC) / 64, 256, 0, stream>>>(
      x, cw, cb, bg, bb, bm, bv, wq, bq, wk, bk, wv, bvv,
      src_b, q_b, k_b, vt_b);
  k_attn<<<BB * HH, 256, 0, stream>>>(q_b, k_b, vt_b, a_b);
  k_out<<<(BB * CC) / 64, 256, 0, stream>>>(a_b, wo, bo, src_b, lg, lb, out);
}